// Round 6
// baseline (130.780 us; speedup 1.0000x reference)
//
#include <hip/hip_runtime.h>
#include <hip/hip_bf16.h>

#define N_NODES 8192
#define IN_FEAT 128
#define OUT_FEAT 64
#define NEG_SLOPE 0.2f
#define TILES (N_NODES / 16)       // 512 row tiles of 16
#define CHUNKS 16                  // split-K chunks
#define JC (N_NODES / CHUNKS)      // 512 columns per chunk
#define KST (JC / 32)              // 16 K-steps per chunk
#define LOG2E 1.44269504088896340736f

using f32x4  = __attribute__((ext_vector_type(4))) float;
using bf16x8 = __attribute__((ext_vector_type(8))) short;

// float -> bf16 bits RNE (k_wh pack, not hot)
static __device__ __forceinline__ short f2bf(float f) {
    unsigned int u = __float_as_uint(f);
    unsigned int r = (u + 0x7FFFu + ((u >> 16) & 1u)) >> 16;
    return (short)r;
}

// hot-path convert: pairs into v_cvt_pk_bf16_f32
static __device__ __forceinline__ short f2bf_fast(float f) {
    __hip_bfloat16 h = __float2bfloat16(f);
    return __builtin_bit_cast(short, h);
}

static __device__ __forceinline__ float exp2_fast(float x) {
    return __builtin_amdgcn_exp2f(x);
}

// ---------------------------------------------------------------------------
// K0: compress adj (int32 0/1, 256 MB) -> bitmask (8 MB), bit j of row i at
// byte i*1024 + j/8, bit j%8 (flat little-endian bit order).
// One wave per adj row: 32 KB fully sequential read, 256 B per instruction.
// __ballot(v>0) bit l = lane l's predicate -> flat bit order falls out.
// ---------------------------------------------------------------------------
__global__ __launch_bounds__(256) void k_cmp(
    const int* __restrict__ adj, unsigned long long* __restrict__ bm)
{
    const int wid  = (blockIdx.x * 256 + (int)threadIdx.x) >> 6;  // 0..8191 = row
    const int lane = threadIdx.x & 63;
    const int* base = adj + (size_t)wid * N_NODES;
    unsigned long long* bmw = bm + (size_t)wid * (N_NODES / 64);  // 128 qwords/row

    for (int g = 0; g < N_NODES / 256; ++g) {          // 32 groups of 256 ints
        const int* p = base + g * 256;
        const int v0 = p[lane];
        const int v1 = p[64 + lane];
        const int v2 = p[128 + lane];
        const int v3 = p[192 + lane];
        unsigned long long m0 = __ballot(v0 > 0);
        unsigned long long m1 = __ballot(v1 > 0);
        unsigned long long m2 = __ballot(v2 > 0);
        unsigned long long m3 = __ballot(v3 > 0);
        if (lane < 4) {
            unsigned long long m = (lane == 0) ? m0 : (lane == 1) ? m1
                                  : (lane == 2) ? m2 : m3;
            bmw[g * 4 + lane] = m;
        }
    }
}

// ---------------------------------------------------------------------------
// K1: Wh = x @ W (fp32); s1/s2 = (Wh@a1/a2)*log2e; Wh packed bf16 into MFMA
// B-fragment layout: whb[((jb*4+fg)*64 + gl*16+cl)*8 + e]
//   = bf16(Wh[jb*32 + gl*8 + e][fg*16 + cl])
// ---------------------------------------------------------------------------
__global__ __launch_bounds__(256) void k_wh(
    const float* __restrict__ x, const float* __restrict__ W,
    const float* __restrict__ a,
    float* __restrict__ s1, float* __restrict__ s2,
    unsigned short* __restrict__ whb)
{
    __shared__ float xs[4][IN_FEAT];
    const int wv   = threadIdx.x >> 6;
    const int lane = threadIdx.x & 63;
    const int row  = blockIdx.x * 4 + wv;

    const float2 xv = *(const float2*)(x + (size_t)row * IN_FEAT + lane * 2);
    xs[wv][lane * 2]     = xv.x;
    xs[wv][lane * 2 + 1] = xv.y;
    __syncthreads();

    float acc = 0.f;
    #pragma unroll
    for (int k = 0; k < IN_FEAT; ++k)
        acc = fmaf(xs[wv][k], W[k * OUT_FEAT + lane], acc);

    float p1 = acc * a[lane];
    float p2 = acc * a[OUT_FEAT + lane];
    #pragma unroll
    for (int off = 32; off; off >>= 1) {
        p1 += __shfl_xor(p1, off);
        p2 += __shfl_xor(p2, off);
    }
    if (lane == 0) {
        s1[row] = p1 * LOG2E;
        s2[row] = p2 * LOG2E;
    }

    const int jb = row >> 5;
    const int ri = row & 31;
    const int gl = ri >> 3;
    const int e  = ri & 7;
    const int fg = lane >> 4;
    const int cl = lane & 15;
    whb[(((size_t)(jb * 4 + fg) * 64) + (gl * 16 + cl)) * 8 + e] = (unsigned short)f2bf(acc);
}

// ---------------------------------------------------------------------------
// K4: main pass, bitmask edition.  2 waves/block, each wave = one 16-row tile
// x 64 feats over a 512-col chunk.  Per step each lane reads ONE bitmask byte
// (bits 0..7 = its 8 columns), s2 as f32x4 pairs (L1-hot), whb fragments
// rotate in registers 1-deep.  No LDS, no HBM streaming here.
// A-fragment: A[m][k], m=lane&15, k=8*(lane>>4)+e.
// ---------------------------------------------------------------------------
__global__ __launch_bounds__(128, 4) void k_attn(
    const unsigned char* __restrict__ bm, const float* __restrict__ s1v,
    const float* __restrict__ s2v, const unsigned short* __restrict__ whb,
    float* __restrict__ pnum, float* __restrict__ pz)
{
    const int lane  = threadIdx.x & 63;
    const int wv    = threadIdx.x >> 6;
    const int tile  = blockIdx.x * 2 + wv;
    const int chunk = blockIdx.y;
    const int cl = lane & 15, g = lane >> 4;
    const int row = tile * 16 + cl;
    const float s1r = s1v[row];
    const int j0 = chunk * JC;

    const unsigned char*  bp  = bm + (size_t)row * (N_NODES / 8) + (j0 >> 3) + g;
    const float*          sp  = s2v + j0 + 8 * g;
    const unsigned short* wbl = whb + (size_t)(j0 >> 5) * 2048 + lane * 8;

    f32x4 acc0 = {0.f, 0.f, 0.f, 0.f};
    f32x4 acc1 = acc0, acc2 = acc0, acc3 = acc0;
    float zacc = 0.f;

    // prefetch step 0
    unsigned int byC = bp[0];
    f32x4 sC0 = *(const f32x4*)(sp);
    f32x4 sC1 = *(const f32x4*)(sp + 4);
    bf16x8 A0 = *(const bf16x8*)(wbl);
    bf16x8 A1 = *(const bf16x8*)(wbl + 512);
    bf16x8 A2 = *(const bf16x8*)(wbl + 1024);
    bf16x8 A3 = *(const bf16x8*)(wbl + 1536);

    for (int t = 0; t < KST; ++t) {
        // prefetch step t+1 (clamped; re-load of same on last iter is harmless)
        const int tn = (t + 1 < KST) ? t + 1 : t;
        unsigned int byN = bp[tn * 4];
        const float* spn = sp + tn * 32;
        f32x4 sN0 = *(const f32x4*)(spn);
        f32x4 sN1 = *(const f32x4*)(spn + 4);
        const unsigned short* wq = wbl + (size_t)tn * 2048;
        bf16x8 B0 = *(const bf16x8*)(wq);
        bf16x8 B1 = *(const bf16x8*)(wq + 512);
        bf16x8 B2 = *(const bf16x8*)(wq + 1024);
        bf16x8 B3 = *(const bf16x8*)(wq + 1536);

        // weights -> A fragment
        bf16x8 af;
        #pragma unroll
        for (int e = 0; e < 4; ++e) {
            float tv = s1r + sC0[e];
            float el = fmaxf(tv, NEG_SLOPE * tv);
            float w  = ((byC >> e) & 1u) ? exp2_fast(el) : 1.0f;
            zacc += w;
            af[e] = f2bf_fast(w);
        }
        #pragma unroll
        for (int e = 0; e < 4; ++e) {
            float tv = s1r + sC1[e];
            float el = fmaxf(tv, NEG_SLOPE * tv);
            float w  = ((byC >> (4 + e)) & 1u) ? exp2_fast(el) : 1.0f;
            zacc += w;
            af[4 + e] = f2bf_fast(w);
        }

        acc0 = __builtin_amdgcn_mfma_f32_16x16x32_bf16(af, A0, acc0, 0, 0, 0);
        acc1 = __builtin_amdgcn_mfma_f32_16x16x32_bf16(af, A1, acc1, 0, 0, 0);
        acc2 = __builtin_amdgcn_mfma_f32_16x16x32_bf16(af, A2, acc2, 0, 0, 0);
        acc3 = __builtin_amdgcn_mfma_f32_16x16x32_bf16(af, A3, acc3, 0, 0, 0);

        byC = byN; sC0 = sN0; sC1 = sN1;
        A0 = B0; A1 = B1; A2 = B2; A3 = B3;
    }

    // Z: combine the 4 lane-groups holding the same row (l&15)
    float z = zacc + __shfl_xor(zacc, 16);
    z += __shfl_xor(z, 32);

    float* pb = pnum + (((size_t)chunk * TILES + tile) * 64 + lane) * 16;
    *(f32x4*)(pb + 0)  = acc0;
    *(f32x4*)(pb + 4)  = acc1;
    *(f32x4*)(pb + 8)  = acc2;
    *(f32x4*)(pb + 12) = acc3;
    if (lane < 16) pz[(size_t)chunk * N_NODES + tile * 16 + lane] = z;
}

// ---------------------------------------------------------------------------
// K5: sum split-K partials, divide by Z, write out.
// D-fragment layout (HW-verified): col = lane&15, row = 4*(lane>>4) + reg.
// ---------------------------------------------------------------------------
__global__ __launch_bounds__(256) void k_out(
    const float* __restrict__ pnum, const float* __restrict__ pz,
    float* __restrict__ out, int nchunks)
{
    const int idx = blockIdx.x * 256 + threadIdx.x;   // < 8192*64
    const int row = idx >> 6, f = idx & 63;
    const int tile = row >> 4, rit = row & 15;
    const int g = rit >> 2, q = rit & 3;
    const int lane = g * 16 + (f & 15);
    const int fg = f >> 4;

    float num = 0.f, z = 0.f;
    for (int c = 0; c < nchunks; ++c) {
        num += pnum[(((size_t)c * TILES + tile) * 64 + lane) * 16 + fg * 4 + q];
        z   += pz[(size_t)c * N_NODES + tile * 16 + rit];
    }
    out[idx] = num / z;
}

// ---------------------------------------------------------------------------
extern "C" void kernel_launch(void* const* d_in, const int* in_sizes, int n_in,
                              void* d_out, int out_size, void* d_ws, size_t ws_size,
                              hipStream_t stream) {
    const float* x   = (const float*)d_in[0];
    const int*   adj = (const int*)d_in[1];
    const float* W   = (const float*)d_in[2];
    const float* a   = (const float*)d_in[3];
    float* out = (float*)d_out;

    char* ws = (char*)d_ws;
    float* s1 = (float*)(ws);                                  // 32 KB
    float* s2 = (float*)(ws + 32 * 1024);                      // 32 KB
    unsigned short* whb = (unsigned short*)(ws + 64 * 1024);   // 1 MB
    unsigned long long* bmq = (unsigned long long*)(ws + 2u * 1024 * 1024);  // 8 MB
    float* pnum = (float*)(ws + 16u * 1024 * 1024);            // 16 x 2 MB = 32 MB
    float* pz   = (float*)(ws + 48u * 1024 * 1024);            // 512 KB

    k_cmp <<<dim3(N_NODES / 4), dim3(256), 0, stream>>>(adj, bmq);
    k_wh  <<<dim3(N_NODES / 4), dim3(256), 0, stream>>>(x, W, a, s1, s2, whb);
    k_attn<<<dim3(TILES / 2, CHUNKS), dim3(128), 0, stream>>>(
        (const unsigned char*)bmq, s1, s2, whb, pnum, pz);
    k_out <<<dim3(N_NODES * OUT_FEAT / 256), dim3(256), 0, stream>>>(pnum, pz, out, CHUNKS);
}

// Round 7
// 117.909 us; speedup vs baseline: 1.1092x; 1.1092x over previous
//
#include <hip/hip_runtime.h>
#include <hip/hip_bf16.h>

#define N_NODES 8192
#define IN_FEAT 128
#define OUT_FEAT 64
#define NEG_SLOPE 0.2f
#define TILES (N_NODES / 16)       // 512 row tiles of 16
#define CHUNKS 16                  // split-K chunks
#define JC (N_NODES / CHUNKS)      // 512 columns per chunk
#define KST (JC / 32)              // 16 K-steps per chunk
#define LOG2E 1.44269504088896340736f

using f32x4  = __attribute__((ext_vector_type(4))) float;
using bf16x8 = __attribute__((ext_vector_type(8))) short;

// float -> bf16 bits RNE (k_wh pack, not hot)
static __device__ __forceinline__ short f2bf(float f) {
    unsigned int u = __float_as_uint(f);
    unsigned int r = (u + 0x7FFFu + ((u >> 16) & 1u)) >> 16;
    return (short)r;
}

// hot-path convert: pairs into v_cvt_pk_bf16_f32
static __device__ __forceinline__ short f2bf_fast(float f) {
    __hip_bfloat16 h = __float2bfloat16(f);
    return __builtin_bit_cast(short, h);
}

static __device__ __forceinline__ float exp2_fast(float x) {
    return __builtin_amdgcn_exp2f(x);
}

// ---------------------------------------------------------------------------
// K0: compress adj (int32 0/1, 256 MB) -> bitmask (8 MB), bit j of row i at
// byte i*1024 + j/8, bit j%8 (flat little-endian bit order).
// One wave per adj row: 32 KB fully sequential read, 256 B per instruction.
// Nontemporal: don't let the once-through 256 MB stream evict L3 (bitmask
// wants to stay resident for k_attn).
// ---------------------------------------------------------------------------
__global__ __launch_bounds__(256) void k_cmp(
    const int* __restrict__ adj, unsigned long long* __restrict__ bm)
{
    const int wid  = (blockIdx.x * 256 + (int)threadIdx.x) >> 6;  // 0..8191 = row
    const int lane = threadIdx.x & 63;
    const int* base = adj + (size_t)wid * N_NODES;
    unsigned long long* bmw = bm + (size_t)wid * (N_NODES / 64);  // 128 qwords/row

    #pragma unroll 2
    for (int g = 0; g < N_NODES / 256; ++g) {          // 32 groups of 256 ints
        const int* p = base + g * 256;
        const int v0 = __builtin_nontemporal_load(p + lane);
        const int v1 = __builtin_nontemporal_load(p + 64 + lane);
        const int v2 = __builtin_nontemporal_load(p + 128 + lane);
        const int v3 = __builtin_nontemporal_load(p + 192 + lane);
        unsigned long long m0 = __ballot(v0 > 0);
        unsigned long long m1 = __ballot(v1 > 0);
        unsigned long long m2 = __ballot(v2 > 0);
        unsigned long long m3 = __ballot(v3 > 0);
        if (lane < 4) {
            unsigned long long m = (lane == 0) ? m0 : (lane == 1) ? m1
                                  : (lane == 2) ? m2 : m3;
            bmw[g * 4 + lane] = m;
        }
    }
}

// ---------------------------------------------------------------------------
// K1: Wh = x @ W (fp32); s1/s2 = (Wh@a1/a2)*log2e; Wh packed bf16 into MFMA
// B-fragment layout: whb[((jb*4+fg)*64 + gl*16+cl)*8 + e]
//   = bf16(Wh[jb*32 + gl*8 + e][fg*16 + cl])
// ---------------------------------------------------------------------------
__global__ __launch_bounds__(256) void k_wh(
    const float* __restrict__ x, const float* __restrict__ W,
    const float* __restrict__ a,
    float* __restrict__ s1, float* __restrict__ s2,
    unsigned short* __restrict__ whb)
{
    __shared__ float xs[4][IN_FEAT];
    const int wv   = threadIdx.x >> 6;
    const int lane = threadIdx.x & 63;
    const int row  = blockIdx.x * 4 + wv;

    const float2 xv = *(const float2*)(x + (size_t)row * IN_FEAT + lane * 2);
    xs[wv][lane * 2]     = xv.x;
    xs[wv][lane * 2 + 1] = xv.y;
    __syncthreads();

    float acc = 0.f;
    #pragma unroll
    for (int k = 0; k < IN_FEAT; ++k)
        acc = fmaf(xs[wv][k], W[k * OUT_FEAT + lane], acc);

    float p1 = acc * a[lane];
    float p2 = acc * a[OUT_FEAT + lane];
    #pragma unroll
    for (int off = 32; off; off >>= 1) {
        p1 += __shfl_xor(p1, off);
        p2 += __shfl_xor(p2, off);
    }
    if (lane == 0) {
        s1[row] = p1 * LOG2E;
        s2[row] = p2 * LOG2E;
    }

    const int jb = row >> 5;
    const int ri = row & 31;
    const int gl = ri >> 3;
    const int e  = ri & 7;
    const int fg = lane >> 4;
    const int cl = lane & 15;
    whb[(((size_t)(jb * 4 + fg) * 64) + (gl * 16 + cl)) * 8 + e] = (unsigned short)f2bf(acc);
}

// ---------------------------------------------------------------------------
// K4: main pass, bitmask edition.  2 waves/block, each wave = one 16-row tile
// x 64 feats over a 512-col chunk.  Per step each lane reads ONE bitmask byte
// (2-deep prefetch), s2 as f32x4 pairs (L1-hot), whb fragments rotate in regs.
// A-fragment: A[m][k], m=lane&15, k=8*(lane>>4)+e.
// pnum stored LANE-MAJOR: pnum[((chunk*TILES+tile)*16 + nt*4+q)*64 + lane]
// so the k_out reduction is fully coalesced.
// ---------------------------------------------------------------------------
__global__ __launch_bounds__(128, 4) void k_attn(
    const unsigned char* __restrict__ bm, const float* __restrict__ s1v,
    const float* __restrict__ s2v, const unsigned short* __restrict__ whb,
    float* __restrict__ pnum, float* __restrict__ pz)
{
    const int lane  = threadIdx.x & 63;
    const int wv    = threadIdx.x >> 6;
    const int tile  = blockIdx.x * 2 + wv;
    const int chunk = blockIdx.y;
    const int cl = lane & 15, g = lane >> 4;
    const int row = tile * 16 + cl;
    const float s1r = s1v[row];
    const int j0 = chunk * JC;

    const unsigned char*  bp  = bm + (size_t)row * (N_NODES / 8) + (j0 >> 3) + g;
    const float*          sp  = s2v + j0 + 8 * g;
    const unsigned short* wbl = whb + (size_t)(j0 >> 5) * 2048 + lane * 8;

    f32x4 acc0 = {0.f, 0.f, 0.f, 0.f};
    f32x4 acc1 = acc0, acc2 = acc0, acc3 = acc0;
    float zacc = 0.f;

    // prefetch: bitmask bytes 2-deep, s2/whb 1-deep
    unsigned int byC = bp[0];
    unsigned int byN = bp[4];
    f32x4 sC0 = *(const f32x4*)(sp);
    f32x4 sC1 = *(const f32x4*)(sp + 4);
    bf16x8 A0 = *(const bf16x8*)(wbl);
    bf16x8 A1 = *(const bf16x8*)(wbl + 512);
    bf16x8 A2 = *(const bf16x8*)(wbl + 1024);
    bf16x8 A3 = *(const bf16x8*)(wbl + 1536);

    for (int t = 0; t < KST; ++t) {
        const int tn  = (t + 1 < KST) ? t + 1 : t;
        const int tnn = (t + 2 < KST) ? t + 2 : tn;
        unsigned int byNN = bp[tnn * 4];
        const float* spn = sp + tn * 32;
        f32x4 sN0 = *(const f32x4*)(spn);
        f32x4 sN1 = *(const f32x4*)(spn + 4);
        const unsigned short* wq = wbl + (size_t)tn * 2048;
        bf16x8 B0 = *(const bf16x8*)(wq);
        bf16x8 B1 = *(const bf16x8*)(wq + 512);
        bf16x8 B2 = *(const bf16x8*)(wq + 1024);
        bf16x8 B3 = *(const bf16x8*)(wq + 1536);

        // weights -> A fragment
        bf16x8 af;
        #pragma unroll
        for (int e = 0; e < 4; ++e) {
            float tv = s1r + sC0[e];
            float el = fmaxf(tv, NEG_SLOPE * tv);
            float w  = ((byC >> e) & 1u) ? exp2_fast(el) : 1.0f;
            zacc += w;
            af[e] = f2bf_fast(w);
        }
        #pragma unroll
        for (int e = 0; e < 4; ++e) {
            float tv = s1r + sC1[e];
            float el = fmaxf(tv, NEG_SLOPE * tv);
            float w  = ((byC >> (4 + e)) & 1u) ? exp2_fast(el) : 1.0f;
            zacc += w;
            af[4 + e] = f2bf_fast(w);
        }

        acc0 = __builtin_amdgcn_mfma_f32_16x16x32_bf16(af, A0, acc0, 0, 0, 0);
        acc1 = __builtin_amdgcn_mfma_f32_16x16x32_bf16(af, A1, acc1, 0, 0, 0);
        acc2 = __builtin_amdgcn_mfma_f32_16x16x32_bf16(af, A2, acc2, 0, 0, 0);
        acc3 = __builtin_amdgcn_mfma_f32_16x16x32_bf16(af, A3, acc3, 0, 0, 0);

        byC = byN; byN = byNN;
        sC0 = sN0; sC1 = sN1;
        A0 = B0; A1 = B1; A2 = B2; A3 = B3;
    }

    // Z: combine the 4 lane-groups holding the same row (l&15)
    float z = zacc + __shfl_xor(zacc, 16);
    z += __shfl_xor(z, 32);

    // lane-major partial store: 16 x 256B coalesced stores
    float* pb = pnum + ((size_t)chunk * TILES + tile) * 16 * 64 + lane;
    #pragma unroll
    for (int q = 0; q < 4; ++q) pb[(0 * 4 + q) * 64] = acc0[q];
    #pragma unroll
    for (int q = 0; q < 4; ++q) pb[(1 * 4 + q) * 64] = acc1[q];
    #pragma unroll
    for (int q = 0; q < 4; ++q) pb[(2 * 4 + q) * 64] = acc2[q];
    #pragma unroll
    for (int q = 0; q < 4; ++q) pb[(3 * 4 + q) * 64] = acc3[q];
    if (lane < 16) pz[(size_t)chunk * N_NODES + tile * 16 + lane] = z;
}

// ---------------------------------------------------------------------------
// K5: sum split-K partials (coalesced 256B loads), divide by Z, write out.
// One wave per (tile, nt): value (lane, q) -> out[node=tile*16+(lane>>4)*4+q]
//                                              [feat=nt*16+(lane&15)]
// ---------------------------------------------------------------------------
__global__ __launch_bounds__(64) void k_out(
    const float* __restrict__ pnum, const float* __restrict__ pz,
    float* __restrict__ out)
{
    const int lane = threadIdx.x;
    const int tile = blockIdx.x;
    const int nt   = blockIdx.y;           // 0..3 feature n-tile
    const int g = lane >> 4, cli = lane & 15;

    float acc[4] = {0.f, 0.f, 0.f, 0.f};
    float zz[4]  = {0.f, 0.f, 0.f, 0.f};
    #pragma unroll
    for (int c = 0; c < CHUNKS; ++c) {
        const float* pb = pnum + (((size_t)c * TILES + tile) * 16 + nt * 4) * 64 + lane;
        #pragma unroll
        for (int q = 0; q < 4; ++q) acc[q] += pb[q * 64];
        const float* zb = pz + (size_t)c * N_NODES + tile * 16 + g * 4;
        #pragma unroll
        for (int q = 0; q < 4; ++q) zz[q] += zb[q];
    }
    #pragma unroll
    for (int q = 0; q < 4; ++q) {
        const int node = tile * 16 + g * 4 + q;
        out[(size_t)node * OUT_FEAT + nt * 16 + cli] = acc[q] / zz[q];
    }
}

// ---------------------------------------------------------------------------
extern "C" void kernel_launch(void* const* d_in, const int* in_sizes, int n_in,
                              void* d_out, int out_size, void* d_ws, size_t ws_size,
                              hipStream_t stream) {
    const float* x   = (const float*)d_in[0];
    const int*   adj = (const int*)d_in[1];
    const float* W   = (const float*)d_in[2];
    const float* a   = (const float*)d_in[3];
    float* out = (float*)d_out;

    char* ws = (char*)d_ws;
    float* s1 = (float*)(ws);                                  // 32 KB
    float* s2 = (float*)(ws + 32 * 1024);                      // 32 KB
    unsigned short* whb = (unsigned short*)(ws + 64 * 1024);   // 1 MB
    unsigned long long* bmq = (unsigned long long*)(ws + 2u * 1024 * 1024);  // 8 MB
    float* pnum = (float*)(ws + 16u * 1024 * 1024);            // 16 x 2 MB = 32 MB
    float* pz   = (float*)(ws + 48u * 1024 * 1024);            // 512 KB

    k_cmp <<<dim3(N_NODES / 4), dim3(256), 0, stream>>>(adj, bmq);
    k_wh  <<<dim3(N_NODES / 4), dim3(256), 0, stream>>>(x, W, a, s1, s2, whb);
    k_attn<<<dim3(TILES / 2, CHUNKS), dim3(128), 0, stream>>>(
        (const unsigned char*)bmq, s1, s2, whb, pnum, pz);
    k_out <<<dim3(TILES, 4), dim3(64), 0, stream>>>(pnum, pz, out);
}

// Round 8
// 90.450 us; speedup vs baseline: 1.4459x; 1.3036x over previous
//
#include <hip/hip_runtime.h>
#include <hip/hip_bf16.h>

#define N_NODES 8192
#define IN_FEAT 128
#define OUT_FEAT 64
#define NEG_SLOPE 0.2f
#define TILES (N_NODES / 16)       // 512 row tiles of 16
#define CCH 2                      // column chunks (split-K partials)
#define COLS (N_NODES / CCH)       // 4096 cols per block
#define SUBC 512                   // cols per sub-chunk (staged unit)
#define NSUB (COLS / SUBC)         // 8 sub-chunks per block
#define KPW 4                      // k-steps per wave per sub (16 ksteps / 4 waves)
#define ROWPAD 520                 // LDS byte stride per row (512 + 8 pad)
#define BUFSZ (16 * ROWPAD)        // one adj-byte buffer (8320 B)
#define LOG2E 1.44269504088896340736f

using f32x4  = __attribute__((ext_vector_type(4))) float;
using i32x4  = __attribute__((ext_vector_type(4))) int;
using bf16x8 = __attribute__((ext_vector_type(8))) short;

// float -> bf16 bits RNE (k_wh pack, not hot)
static __device__ __forceinline__ short f2bf(float f) {
    unsigned int u = __float_as_uint(f);
    unsigned int r = (u + 0x7FFFu + ((u >> 16) & 1u)) >> 16;
    return (short)r;
}

// hot-path convert: pairs into v_cvt_pk_bf16_f32
static __device__ __forceinline__ short f2bf_fast(float f) {
    __hip_bfloat16 h = __float2bfloat16(f);
    return __builtin_bit_cast(short, h);
}

static __device__ __forceinline__ float exp2_fast(float x) {
    return __builtin_amdgcn_exp2f(x);
}

// ---------------------------------------------------------------------------
// K1: Wh = x @ W (fp32); s1/s2 = (Wh@a1/a2)*log2e; Wh packed bf16 into MFMA
// B-fragment layout: whb[((jb*4+fg)*64 + gl*16+cl)*8 + e]
//   = bf16(Wh[jb*32 + gl*8 + e][fg*16 + cl])
// ---------------------------------------------------------------------------
__global__ __launch_bounds__(256) void k_wh(
    const float* __restrict__ x, const float* __restrict__ W,
    const float* __restrict__ a,
    float* __restrict__ s1, float* __restrict__ s2,
    unsigned short* __restrict__ whb)
{
    __shared__ float xs[4][IN_FEAT];
    const int wv   = threadIdx.x >> 6;
    const int lane = threadIdx.x & 63;
    const int row  = blockIdx.x * 4 + wv;

    const float2 xv = *(const float2*)(x + (size_t)row * IN_FEAT + lane * 2);
    xs[wv][lane * 2]     = xv.x;
    xs[wv][lane * 2 + 1] = xv.y;
    __syncthreads();

    float acc = 0.f;
    #pragma unroll
    for (int k = 0; k < IN_FEAT; ++k)
        acc = fmaf(xs[wv][k], W[k * OUT_FEAT + lane], acc);

    float p1 = acc * a[lane];
    float p2 = acc * a[OUT_FEAT + lane];
    #pragma unroll
    for (int off = 32; off; off >>= 1) {
        p1 += __shfl_xor(p1, off);
        p2 += __shfl_xor(p2, off);
    }
    if (lane == 0) {
        s1[row] = p1 * LOG2E;
        s2[row] = p2 * LOG2E;
    }

    const int jb = row >> 5;
    const int ri = row & 31;
    const int gl = ri >> 3;
    const int e  = ri & 7;
    const int fg = lane >> 4;
    const int cl = lane & 15;
    whb[(((size_t)(jb * 4 + fg) * 64) + (gl * 16 + cl)) * 8 + e] = (unsigned short)f2bf(acc);
}

// ---------------------------------------------------------------------------
// K2 (fused): adj read ONCE at 1KB/instr, packed int32->byte in-register,
// double-buffered through LDS, consumed by MFMA in the same block.
// Block = 4 waves = one 16-row tile x 4096-col half. Wave w stages rows
// 4w..4w+3 of the next sub-chunk while computing k-steps 4w..4w+3 of the
// current one. Cross-wave acc reduction via LDS at the end.
// A-fragment: A[m][k], m=lane&15, k=8*(lane>>4)+e.
// ---------------------------------------------------------------------------
__global__ __launch_bounds__(256, 4) void k_fused(
    const int* __restrict__ adj, const float* __restrict__ s1v,
    const float* __restrict__ s2v, const unsigned short* __restrict__ whb,
    float* __restrict__ pnum, float* __restrict__ pz)
{
    __shared__ __align__(16) char lds[2 * BUFSZ + 256];
    char*  bufs = lds;
    float* zl   = (float*)(lds + 2 * BUFSZ);
    float* red  = (float*)lds;               // aliases bufs (used after final barrier)

    const int lane = threadIdx.x & 63;
    const int w    = threadIdx.x >> 6;
    const int tile = blockIdx.x;
    const int cidx = blockIdx.y;
    const int c0   = cidx * COLS;
    const int cl = lane & 15, g = lane >> 4;
    const int row = tile * 16 + cl;
    const float s1r = s1v[row];

    // stage source: wave w, row rr (0..3), q (0..1): 1KB contiguous per load
    const int* stg = adj + ((size_t)(tile * 16 + w * 4)) * N_NODES + c0 + lane * 4;

    f32x4 acc0 = {0.f, 0.f, 0.f, 0.f};
    f32x4 acc1 = acc0, acc2 = acc0, acc3 = acc0;
    float zacc = 0.f;

    // ---- prologue: stage sub-chunk 0 into buf0 ----
    {
        i32x4 ld[8];
        #pragma unroll
        for (int rr = 0; rr < 4; ++rr)
            #pragma unroll
            for (int q = 0; q < 2; ++q)
                ld[rr * 2 + q] = __builtin_nontemporal_load(
                    (const i32x4*)(stg + (size_t)rr * N_NODES + q * 256));
        #pragma unroll
        for (int rr = 0; rr < 4; ++rr)
            #pragma unroll
            for (int q = 0; q < 2; ++q) {
                i32x4 v = ld[rr * 2 + q];
                unsigned int d = (v[0] > 0 ? 1u : 0u) | (v[1] > 0 ? 0x100u : 0u)
                               | (v[2] > 0 ? 0x10000u : 0u) | (v[3] > 0 ? 0x1000000u : 0u);
                *(unsigned int*)(bufs + (w * 4 + rr) * ROWPAD + q * 256 + lane * 4) = d;
            }
        __syncthreads();
    }

    // ---- main loop over sub-chunks ----
    for (int c = 0; c < NSUB; ++c) {
        const char* rbuf = bufs + (c & 1) * BUFSZ;
        const bool more = (c + 1 < NSUB);

        // issue next sub-chunk's loads BEFORE compute (pinned by sched_barrier)
        i32x4 ld[8];
        if (more) {
            #pragma unroll
            for (int rr = 0; rr < 4; ++rr)
                #pragma unroll
                for (int q = 0; q < 2; ++q)
                    ld[rr * 2 + q] = __builtin_nontemporal_load(
                        (const i32x4*)(stg + (size_t)rr * N_NODES + (c + 1) * SUBC + q * 256));
        }
        __builtin_amdgcn_sched_barrier(0);

        // compute this wave's 4 k-steps on the current buffer
        #pragma unroll
        for (int kk = 0; kk < KPW; ++kk) {
            const int ks = w * KPW + kk;                       // k-step in sub (0..15)
            const uint2 ab = *(const uint2*)(rbuf + cl * ROWPAD + ks * 32 + 8 * g);
            const float* sp = s2v + c0 + c * SUBC + ks * 32 + 8 * g;
            const f32x4 s0  = *(const f32x4*)(sp);
            const f32x4 s1x = *(const f32x4*)(sp + 4);
            const unsigned short* wq =
                whb + ((size_t)(c0 / 32 + c * 16 + ks)) * 2048 + lane * 8;
            bf16x8 B0 = *(const bf16x8*)(wq);
            bf16x8 B1 = *(const bf16x8*)(wq + 512);
            bf16x8 B2 = *(const bf16x8*)(wq + 1024);
            bf16x8 B3 = *(const bf16x8*)(wq + 1536);

            bf16x8 af;
            #pragma unroll
            for (int e = 0; e < 4; ++e) {
                float tv = s1r + s0[e];
                float el = fmaxf(tv, NEG_SLOPE * tv);
                float wv = ((ab.x >> (8 * e)) & 1u) ? exp2_fast(el) : 1.0f;
                zacc += wv;
                af[e] = f2bf_fast(wv);
            }
            #pragma unroll
            for (int e = 0; e < 4; ++e) {
                float tv = s1r + s1x[e];
                float el = fmaxf(tv, NEG_SLOPE * tv);
                float wv = ((ab.y >> (8 * e)) & 1u) ? exp2_fast(el) : 1.0f;
                zacc += wv;
                af[4 + e] = f2bf_fast(wv);
            }

            acc0 = __builtin_amdgcn_mfma_f32_16x16x32_bf16(af, B0, acc0, 0, 0, 0);
            acc1 = __builtin_amdgcn_mfma_f32_16x16x32_bf16(af, B1, acc1, 0, 0, 0);
            acc2 = __builtin_amdgcn_mfma_f32_16x16x32_bf16(af, B2, acc2, 0, 0, 0);
            acc3 = __builtin_amdgcn_mfma_f32_16x16x32_bf16(af, B3, acc3, 0, 0, 0);
        }

        // pack + write next buffer (waits on ld automatically)
        if (more) {
            char* wbuf = bufs + ((c + 1) & 1) * BUFSZ;
            #pragma unroll
            for (int rr = 0; rr < 4; ++rr)
                #pragma unroll
                for (int q = 0; q < 2; ++q) {
                    i32x4 v = ld[rr * 2 + q];
                    unsigned int d = (v[0] > 0 ? 1u : 0u) | (v[1] > 0 ? 0x100u : 0u)
                                   | (v[2] > 0 ? 0x10000u : 0u) | (v[3] > 0 ? 0x1000000u : 0u);
                    *(unsigned int*)(wbuf + (w * 4 + rr) * ROWPAD + q * 256 + lane * 4) = d;
                }
        }
        __syncthreads();
    }

    // ---- cross-wave reduction (red aliases bufs; all reads of bufs are done) ----
    *(f32x4*)(red + ((size_t)(w * 64 + lane)) * 16 + 0)  = acc0;
    *(f32x4*)(red + ((size_t)(w * 64 + lane)) * 16 + 4)  = acc1;
    *(f32x4*)(red + ((size_t)(w * 64 + lane)) * 16 + 8)  = acc2;
    *(f32x4*)(red + ((size_t)(w * 64 + lane)) * 16 + 12) = acc3;
    float zz = zacc + __shfl_xor(zacc, 16);
    zz += __shfl_xor(zz, 32);
    if (lane < 16) zl[w * 16 + lane] = zz;
    __syncthreads();

    f32x4 rs = {0.f, 0.f, 0.f, 0.f};
    #pragma unroll
    for (int w2 = 0; w2 < 4; ++w2)
        rs += *(const f32x4*)(red + ((size_t)(w2 * 64 + lane)) * 16 + 4 * w);

    // lane-major partial store: piece p = w*4+q  ->  pnum[(.. *16 + p)*64 + lane]
    float* pb = pnum + ((size_t)cidx * TILES + tile) * 16 * 64 + lane;
    #pragma unroll
    for (int q = 0; q < 4; ++q) pb[(w * 4 + q) * 64] = rs[q];

    if (w == 0 && lane < 16) {
        float z = zl[lane] + zl[16 + lane] + zl[32 + lane] + zl[48 + lane];
        pz[(size_t)cidx * N_NODES + tile * 16 + lane] = z;
    }
}

// ---------------------------------------------------------------------------
// K3: sum the 2 split-K partials (coalesced 256B loads), divide by Z, write.
// One wave per (tile, nt): value (lane, q) -> out[node=tile*16+(lane>>4)*4+q]
//                                              [feat=nt*16+(lane&15)]
// ---------------------------------------------------------------------------
__global__ __launch_bounds__(64) void k_out(
    const float* __restrict__ pnum, const float* __restrict__ pz,
    float* __restrict__ out)
{
    const int lane = threadIdx.x;
    const int tile = blockIdx.x;
    const int nt   = blockIdx.y;           // 0..3 feature n-tile
    const int g = lane >> 4, cli = lane & 15;

    float acc[4] = {0.f, 0.f, 0.f, 0.f};
    float zz[4]  = {0.f, 0.f, 0.f, 0.f};
    #pragma unroll
    for (int c = 0; c < CCH; ++c) {
        const float* pb = pnum + (((size_t)c * TILES + tile) * 16 + nt * 4) * 64 + lane;
        #pragma unroll
        for (int q = 0; q < 4; ++q) acc[q] += pb[q * 64];
        const float* zb = pz + (size_t)c * N_NODES + tile * 16 + g * 4;
        #pragma unroll
        for (int q = 0; q < 4; ++q) zz[q] += zb[q];
    }
    #pragma unroll
    for (int q = 0; q < 4; ++q) {
        const int node = tile * 16 + g * 4 + q;
        out[(size_t)node * OUT_FEAT + nt * 16 + cli] = acc[q] / zz[q];
    }
}

// ---------------------------------------------------------------------------
extern "C" void kernel_launch(void* const* d_in, const int* in_sizes, int n_in,
                              void* d_out, int out_size, void* d_ws, size_t ws_size,
                              hipStream_t stream) {
    const float* x   = (const float*)d_in[0];
    const int*   adj = (const int*)d_in[1];
    const float* W   = (const float*)d_in[2];
    const float* a   = (const float*)d_in[3];
    float* out = (float*)d_out;

    char* ws = (char*)d_ws;
    float* s1 = (float*)(ws);                                  // 32 KB
    float* s2 = (float*)(ws + 32 * 1024);                      // 32 KB
    unsigned short* whb = (unsigned short*)(ws + 64 * 1024);   // 1 MB
    float* pnum = (float*)(ws + 2u * 1024 * 1024);             // CCH x 2 MB
    float* pz   = (float*)(ws + 8u * 1024 * 1024);             // CCH x 32 KB

    k_wh   <<<dim3(N_NODES / 4), dim3(256), 0, stream>>>(x, W, a, s1, s2, whb);
    k_fused<<<dim3(TILES, CCH), dim3(256), 0, stream>>>(adj, s1, s2, whb, pnum, pz);
    k_out  <<<dim3(TILES, 4), dim3(64), 0, stream>>>(pnum, pz, out);
}

// Round 9
// 87.508 us; speedup vs baseline: 1.4945x; 1.0336x over previous
//
#include <hip/hip_runtime.h>
#include <hip/hip_bf16.h>

#define N_NODES 8192
#define IN_FEAT 128
#define OUT_FEAT 64
#define NEG_SLOPE 0.2f
#define TILES (N_NODES / 16)       // 512 row tiles of 16
#define CCH 2                      // column chunks (split-K partials)
#define COLS (N_NODES / CCH)       // 4096 cols per block
#define SUBC 512                   // cols per sub-chunk (staged unit)
#define NSUB (COLS / SUBC)         // 8 sub-chunks per block
#define KPW 4                      // k-steps per wave per sub (16 ksteps / 4 waves)
#define ROWPAD 528                 // LDS byte stride per packed row (512 + 16: 2-way banks = free)
#define BUFSZ (16 * ROWPAD)        // one adj-byte buffer (8448 B)
#define LOG2E 1.44269504088896340736f

using f32x4  = __attribute__((ext_vector_type(4))) float;
using i32x4  = __attribute__((ext_vector_type(4))) int;
using bf16x8 = __attribute__((ext_vector_type(8))) short;

// float -> bf16 bits RNE (k_wh pack, not hot)
static __device__ __forceinline__ short f2bf(float f) {
    unsigned int u = __float_as_uint(f);
    unsigned int r = (u + 0x7FFFu + ((u >> 16) & 1u)) >> 16;
    return (short)r;
}

// hot-path convert: pairs into v_cvt_pk_bf16_f32
static __device__ __forceinline__ short f2bf_fast(float f) {
    __hip_bfloat16 h = __float2bfloat16(f);
    return __builtin_bit_cast(short, h);
}

static __device__ __forceinline__ float exp2_fast(float x) {
    return __builtin_amdgcn_exp2f(x);
}

// ---------------------------------------------------------------------------
// K1: Wh = x @ W (fp32); s1/s2 = (Wh@a1/a2)*log2e; Wh packed bf16 into MFMA
// B-fragment layout: whb[((jb*4+fg)*64 + gl*16+cl)*8 + e]
//   = bf16(Wh[jb*32 + gl*8 + e][fg*16 + cl])
// ---------------------------------------------------------------------------
__global__ __launch_bounds__(256) void k_wh(
    const float* __restrict__ x, const float* __restrict__ W,
    const float* __restrict__ a,
    float* __restrict__ s1, float* __restrict__ s2,
    unsigned short* __restrict__ whb)
{
    __shared__ float xs[4][IN_FEAT];
    const int wv   = threadIdx.x >> 6;
    const int lane = threadIdx.x & 63;
    const int row  = blockIdx.x * 4 + wv;

    const float2 xv = *(const float2*)(x + (size_t)row * IN_FEAT + lane * 2);
    xs[wv][lane * 2]     = xv.x;
    xs[wv][lane * 2 + 1] = xv.y;
    __syncthreads();

    float acc = 0.f;
    #pragma unroll
    for (int k = 0; k < IN_FEAT; ++k)
        acc = fmaf(xs[wv][k], W[k * OUT_FEAT + lane], acc);

    float p1 = acc * a[lane];
    float p2 = acc * a[OUT_FEAT + lane];
    #pragma unroll
    for (int off = 32; off; off >>= 1) {
        p1 += __shfl_xor(p1, off);
        p2 += __shfl_xor(p2, off);
    }
    if (lane == 0) {
        s1[row] = p1 * LOG2E;
        s2[row] = p2 * LOG2E;
    }

    const int jb = row >> 5;
    const int ri = row & 31;
    const int gl = ri >> 3;
    const int e  = ri & 7;
    const int fg = lane >> 4;
    const int cl = lane & 15;
    whb[(((size_t)(jb * 4 + fg) * 64) + (gl * 16 + cl)) * 8 + e] = (unsigned short)f2bf(acc);
}

// ---------------------------------------------------------------------------
// K2 (fused, pipelined): adj read ONCE at 1KB/instr. Per round:
//   pack(c+1) [arrived last round] -> issue(c+2) into same regs -> compute(c)
//   -> s_waitcnt lgkmcnt(0) -> raw s_barrier  (NO vmcnt drain at the barrier!)
// s2 chunk staged to LDS in prologue so the exp/VALU path has no vmcnt dep.
// A-fragment: A[m][k], m=lane&15, k=8*(lane>>4)+e.
// ---------------------------------------------------------------------------
__global__ __launch_bounds__(256, 4) void k_fused(
    const int* __restrict__ adj, const float* __restrict__ s1v,
    const float* __restrict__ s2v, const unsigned short* __restrict__ whb,
    float* __restrict__ pnum, float* __restrict__ pz)
{
    __shared__ __align__(16) char lds[2 * BUFSZ + COLS * 4 + 256];
    char*  bufs = lds;                               // 2 x 8448 adj-byte buffers
    float* s2l  = (float*)(lds + 2 * BUFSZ);         // 4096 floats (16 KB)
    float* zl   = (float*)(lds + 2 * BUFSZ + COLS * 4);
    float* red  = (float*)lds;                       // aliases bufs (post-loop)

    const int lane = threadIdx.x & 63;
    const int w    = threadIdx.x >> 6;
    const int tile = blockIdx.x;
    const int cidx = blockIdx.y;
    const int c0   = cidx * COLS;
    const int cl = lane & 15, g = lane >> 4;
    const int row = tile * 16 + cl;
    const float s1r = s1v[row];

    // stage source: wave w, rows 4w..4w+3; 1KB contiguous per load instr
    const int* stg = adj + ((size_t)(tile * 16 + w * 4)) * N_NODES + c0 + lane * 4;

    i32x4 ld[8];

    auto issue = [&](int c) {
        #pragma unroll
        for (int rr = 0; rr < 4; ++rr)
            #pragma unroll
            for (int q = 0; q < 2; ++q)
                ld[rr * 2 + q] = __builtin_nontemporal_load(
                    (const i32x4*)(stg + (size_t)rr * N_NODES + c * SUBC + q * 256));
    };
    auto pack = [&](int c) {   // write packed bytes of sub-chunk c into buf[c&1]
        char* wbuf = bufs + (c & 1) * BUFSZ;
        #pragma unroll
        for (int rr = 0; rr < 4; ++rr)
            #pragma unroll
            for (int q = 0; q < 2; ++q) {
                i32x4 v = ld[rr * 2 + q];
                unsigned int d = (v[0] > 0 ? 1u : 0u) | (v[1] > 0 ? 0x100u : 0u)
                               | (v[2] > 0 ? 0x10000u : 0u) | (v[3] > 0 ? 0x1000000u : 0u);
                *(unsigned int*)(wbuf + (w * 4 + rr) * ROWPAD + q * 256 + lane * 4) = d;
            }
    };

    f32x4 acc0 = {0.f, 0.f, 0.f, 0.f};
    f32x4 acc1 = acc0, acc2 = acc0, acc3 = acc0;
    float zacc = 0.f;

    auto compute = [&](int c) {
        const char* rbuf = bufs + (c & 1) * BUFSZ;
        #pragma unroll
        for (int kk = 0; kk < KPW; ++kk) {
            const int ks = w * KPW + kk;                   // k-step in sub (0..15)
            const uint2 ab = *(const uint2*)(rbuf + cl * ROWPAD + ks * 32 + 8 * g);
            const float* sp = s2l + c * SUBC + ks * 32 + 8 * g;
            const f32x4 s0  = *(const f32x4*)(sp);
            const f32x4 s1x = *(const f32x4*)(sp + 4);
            const unsigned short* wq =
                whb + ((size_t)(c0 / 32 + c * 16 + ks)) * 2048 + lane * 8;
            bf16x8 B0 = *(const bf16x8*)(wq);
            bf16x8 B1 = *(const bf16x8*)(wq + 512);
            bf16x8 B2 = *(const bf16x8*)(wq + 1024);
            bf16x8 B3 = *(const bf16x8*)(wq + 1536);

            bf16x8 af;
            #pragma unroll
            for (int e = 0; e < 4; ++e) {
                float tv = s1r + s0[e];
                float el = fmaxf(tv, NEG_SLOPE * tv);
                float wv = ((ab.x >> (8 * e)) & 1u) ? exp2_fast(el) : 1.0f;
                zacc += wv;
                af[e] = f2bf_fast(wv);
            }
            #pragma unroll
            for (int e = 0; e < 4; ++e) {
                float tv = s1r + s1x[e];
                float el = fmaxf(tv, NEG_SLOPE * tv);
                float wv = ((ab.y >> (8 * e)) & 1u) ? exp2_fast(el) : 1.0f;
                zacc += wv;
                af[4 + e] = f2bf_fast(wv);
            }

            acc0 = __builtin_amdgcn_mfma_f32_16x16x32_bf16(af, B0, acc0, 0, 0, 0);
            acc1 = __builtin_amdgcn_mfma_f32_16x16x32_bf16(af, B1, acc1, 0, 0, 0);
            acc2 = __builtin_amdgcn_mfma_f32_16x16x32_bf16(af, B2, acc2, 0, 0, 0);
            acc3 = __builtin_amdgcn_mfma_f32_16x16x32_bf16(af, B3, acc3, 0, 0, 0);
        }
    };

    // ---- prologue: s2 slice -> LDS; L0 arrive+pack; L1 in flight ----
    {
        const float* src = s2v + c0 + threadIdx.x * 4;
        float* dst = s2l + threadIdx.x * 4;
        #pragma unroll
        for (int i = 0; i < 4; ++i)
            *(f32x4*)(dst + i * 1024) = *(const f32x4*)(src + i * 1024);
    }
    issue(0);
    pack(0);          // auto s_waitcnt for L0 regs
    issue(1);         // L1 in flight across the barrier
    __builtin_amdgcn_sched_barrier(0);
    asm volatile("s_waitcnt lgkmcnt(0)" ::: "memory");
    __builtin_amdgcn_s_barrier();
    __builtin_amdgcn_sched_barrier(0);

    // ---- main rounds: pack(c+1) -> issue(c+2) -> compute(c) -> lgkm+barrier
    for (int c = 0; c < NSUB; ++c) {
        if (c + 1 < NSUB) pack(c + 1);
        __builtin_amdgcn_sched_barrier(0);
        if (c + 2 < NSUB) issue(c + 2);
        __builtin_amdgcn_sched_barrier(0);
        compute(c);
        __builtin_amdgcn_sched_barrier(0);
        asm volatile("s_waitcnt lgkmcnt(0)" ::: "memory");
        __builtin_amdgcn_s_barrier();
        __builtin_amdgcn_sched_barrier(0);
    }

    // ---- cross-wave reduction (red aliases bufs; last barrier protects) ----
    *(f32x4*)(red + ((size_t)(w * 64 + lane)) * 16 + 0)  = acc0;
    *(f32x4*)(red + ((size_t)(w * 64 + lane)) * 16 + 4)  = acc1;
    *(f32x4*)(red + ((size_t)(w * 64 + lane)) * 16 + 8)  = acc2;
    *(f32x4*)(red + ((size_t)(w * 64 + lane)) * 16 + 12) = acc3;
    float zz = zacc + __shfl_xor(zacc, 16);
    zz += __shfl_xor(zz, 32);
    if (lane < 16) zl[w * 16 + lane] = zz;
    __syncthreads();

    f32x4 rs = {0.f, 0.f, 0.f, 0.f};
    #pragma unroll
    for (int w2 = 0; w2 < 4; ++w2)
        rs += *(const f32x4*)(red + ((size_t)(w2 * 64 + lane)) * 16 + 4 * w);

    float* pb = pnum + ((size_t)cidx * TILES + tile) * 16 * 64 + lane;
    #pragma unroll
    for (int q = 0; q < 4; ++q) pb[(w * 4 + q) * 64] = rs[q];

    if (w == 0 && lane < 16) {
        float z = zl[lane] + zl[16 + lane] + zl[32 + lane] + zl[48 + lane];
        pz[(size_t)cidx * N_NODES + tile * 16 + lane] = z;
    }
}

// ---------------------------------------------------------------------------
// K3: sum the 2 split-K partials (coalesced 256B loads), divide by Z, write.
// ---------------------------------------------------------------------------
__global__ __launch_bounds__(64) void k_out(
    const float* __restrict__ pnum, const float* __restrict__ pz,
    float* __restrict__ out)
{
    const int lane = threadIdx.x;
    const int tile = blockIdx.x;
    const int nt   = blockIdx.y;           // 0..3 feature n-tile
    const int g = lane >> 4, cli = lane & 15;

    float acc[4] = {0.f, 0.f, 0.f, 0.f};
    float zz[4]  = {0.f, 0.f, 0.f, 0.f};
    #pragma unroll
    for (int c = 0; c < CCH; ++c) {
        const float* pb = pnum + (((size_t)c * TILES + tile) * 16 + nt * 4) * 64 + lane;
        #pragma unroll
        for (int q = 0; q < 4; ++q) acc[q] += pb[q * 64];
        const float* zb = pz + (size_t)c * N_NODES + tile * 16 + g * 4;
        #pragma unroll
        for (int q = 0; q < 4; ++q) zz[q] += zb[q];
    }
    #pragma unroll
    for (int q = 0; q < 4; ++q) {
        const int node = tile * 16 + g * 4 + q;
        out[(size_t)node * OUT_FEAT + nt * 16 + cli] = acc[q] / zz[q];
    }
}

// ---------------------------------------------------------------------------
extern "C" void kernel_launch(void* const* d_in, const int* in_sizes, int n_in,
                              void* d_out, int out_size, void* d_ws, size_t ws_size,
                              hipStream_t stream) {
    const float* x   = (const float*)d_in[0];
    const int*   adj = (const int*)d_in[1];
    const float* W   = (const float*)d_in[2];
    const float* a   = (const float*)d_in[3];
    float* out = (float*)d_out;

    char* ws = (char*)d_ws;
    float* s1 = (float*)(ws);                                  // 32 KB
    float* s2 = (float*)(ws + 32 * 1024);                      // 32 KB
    unsigned short* whb = (unsigned short*)(ws + 64 * 1024);   // 1 MB
    float* pnum = (float*)(ws + 2u * 1024 * 1024);             // CCH x 2 MB
    float* pz   = (float*)(ws + 8u * 1024 * 1024);             // CCH x 32 KB

    k_wh   <<<dim3(N_NODES / 4), dim3(256), 0, stream>>>(x, W, a, s1, s2, whb);
    k_fused<<<dim3(TILES, CCH), dim3(256), 0, stream>>>(adj, s1, s2, whb, pnum, pz);
    k_out  <<<dim3(TILES, 4), dim3(64), 0, stream>>>(pnum, pz, out);
}

// Round 10
// 85.727 us; speedup vs baseline: 1.5255x; 1.0208x over previous
//
#include <hip/hip_runtime.h>
#include <hip/hip_bf16.h>

#define N_NODES 8192
#define IN_FEAT 128
#define OUT_FEAT 64
#define NEG_SLOPE 0.2f
#define TILES (N_NODES / 16)       // 512 row tiles of 16 -> grid, 2 blocks/CU
#define SUBC 512                   // cols per sub-chunk (staged unit)
#define NSUB (N_NODES / SUBC)      // 16 rounds
#define KPW 4                      // k-steps per consumer wave per round
#define ROWPAD 528                 // LDS byte stride per packed row
#define BUFSZ (16 * ROWPAD)        // one adj-byte buffer (8448 B)
#define LOG2E 1.44269504088896340736f

using f32x4  = __attribute__((ext_vector_type(4))) float;
using i32x4  = __attribute__((ext_vector_type(4))) int;
using bf16x8 = __attribute__((ext_vector_type(8))) short;

// float -> bf16 bits RNE (k_wh pack, not hot)
static __device__ __forceinline__ short f2bf(float f) {
    unsigned int u = __float_as_uint(f);
    unsigned int r = (u + 0x7FFFu + ((u >> 16) & 1u)) >> 16;
    return (short)r;
}

// hot-path convert: pairs into v_cvt_pk_bf16_f32
static __device__ __forceinline__ short f2bf_fast(float f) {
    __hip_bfloat16 h = __float2bfloat16(f);
    return __builtin_bit_cast(short, h);
}

static __device__ __forceinline__ float exp2_fast(float x) {
    return __builtin_amdgcn_exp2f(x);
}

// ---------------------------------------------------------------------------
// K1: Wh = x @ W (fp32); s1/s2 = (Wh@a1/a2)*log2e; Wh packed bf16 into MFMA
// B-fragment layout: whb[((jb*4+fg)*64 + gl*16+cl)*8 + e]
//   = bf16(Wh[jb*32 + gl*8 + e][fg*16 + cl])
// ---------------------------------------------------------------------------
__global__ __launch_bounds__(256) void k_wh(
    const float* __restrict__ x, const float* __restrict__ W,
    const float* __restrict__ a,
    float* __restrict__ s1, float* __restrict__ s2,
    unsigned short* __restrict__ whb)
{
    __shared__ float xs[4][IN_FEAT];
    const int wv   = threadIdx.x >> 6;
    const int lane = threadIdx.x & 63;
    const int row  = blockIdx.x * 4 + wv;

    const float2 xv = *(const float2*)(x + (size_t)row * IN_FEAT + lane * 2);
    xs[wv][lane * 2]     = xv.x;
    xs[wv][lane * 2 + 1] = xv.y;
    __syncthreads();

    float acc = 0.f;
    #pragma unroll
    for (int k = 0; k < IN_FEAT; ++k)
        acc = fmaf(xs[wv][k], W[k * OUT_FEAT + lane], acc);

    float p1 = acc * a[lane];
    float p2 = acc * a[OUT_FEAT + lane];
    #pragma unroll
    for (int off = 32; off; off >>= 1) {
        p1 += __shfl_xor(p1, off);
        p2 += __shfl_xor(p2, off);
    }
    if (lane == 0) {
        s1[row] = p1 * LOG2E;
        s2[row] = p2 * LOG2E;
    }

    const int jb = row >> 5;
    const int ri = row & 31;
    const int gl = ri >> 3;
    const int e  = ri & 7;
    const int fg = lane >> 4;
    const int cl = lane & 15;
    whb[(((size_t)(jb * 4 + fg) * 64) + (gl * 16 + cl)) * 8 + e] = (unsigned short)f2bf(acc);
}

// ---------------------------------------------------------------------------
// K2 (fused, producer/consumer): 8 waves. Waves 0-3 stream adj (1KB/instr NT,
// two reg sets ping-ponged: issue(c+2) BEFORE pack(c+1) -> wait is vmcnt(8),
// 8KB/wave always in flight, never drains). Waves 4-7 compute: their vmcnt
// chain holds ONLY L2-hot whb loads -- decoupled from the adj stream.
// One barrier per round. No split-K: block reduces in LDS, writes out.
// A-fragment: A[m][k], m=lane&15, k=8*(lane>>4)+e.
// ---------------------------------------------------------------------------
__global__ __launch_bounds__(512, 4) void k_fused(
    const int* __restrict__ adj, const float* __restrict__ s1v,
    const float* __restrict__ s2v, const unsigned short* __restrict__ whb,
    float* __restrict__ out)
{
    __shared__ __align__(16) char lds[2 * BUFSZ + N_NODES * 4 + 256];
    char*  bufs = lds;                                   // 2 x 8448 adj-byte bufs
    float* s2l  = (float*)(lds + 2 * BUFSZ);             // 8192 floats (32 KB)
    float* zl   = (float*)(lds + 2 * BUFSZ + N_NODES * 4);
    float* red  = (float*)lds;                           // aliases bufs (post-loop)

    const int tid  = threadIdx.x;
    const int lane = tid & 63;
    const int w    = tid >> 6;                           // 0..7
    const int tile = blockIdx.x;
    const int cl = lane & 15, g = lane >> 4;

    // ---- s2 -> LDS (all 512 threads, 16 floats each) ----
    {
        const float* src = s2v + tid * 4;
        #pragma unroll
        for (int i = 0; i < 4; ++i)
            *(f32x4*)(s2l + tid * 4 + i * 2048) = *(const f32x4*)(src + i * 2048);
    }

    if (w < 4) {
        // ========================= PRODUCER =========================
        const int* stg = adj + ((size_t)(tile * 16 + w * 4)) * N_NODES + lane * 4;
        i32x4 ldA[8], ldB[8];

        auto issue = [&](i32x4 (&ld)[8], int c) {
            #pragma unroll
            for (int rr = 0; rr < 4; ++rr)
                #pragma unroll
                for (int q = 0; q < 2; ++q)
                    ld[rr * 2 + q] = __builtin_nontemporal_load(
                        (const i32x4*)(stg + (size_t)rr * N_NODES + c * SUBC + q * 256));
        };
        auto pack = [&](i32x4 (&ld)[8], int c) {
            char* wbuf = bufs + (c & 1) * BUFSZ;
            #pragma unroll
            for (int rr = 0; rr < 4; ++rr)
                #pragma unroll
                for (int q = 0; q < 2; ++q) {
                    i32x4 v = ld[rr * 2 + q];
                    unsigned int d = (v[0] > 0 ? 1u : 0u) | (v[1] > 0 ? 0x100u : 0u)
                                   | (v[2] > 0 ? 0x10000u : 0u) | (v[3] > 0 ? 0x1000000u : 0u);
                    *(unsigned int*)(wbuf + (w * 4 + rr) * ROWPAD + q * 256 + lane * 4) = d;
                }
        };

        // prologue: both sets in flight, pack(0) waits vmcnt(8)
        issue(ldA, 0);
        issue(ldB, 1);
        pack(ldA, 0);
        asm volatile("s_waitcnt lgkmcnt(0)" ::: "memory");
        __builtin_amdgcn_s_barrier();                    // B0 (prologue)

        for (int c = 0; c < NSUB; c += 2) {
            // even round c: issue(c+2)->A, pack(c+1) from B
            if (c + 2 < NSUB) issue(ldA, c + 2);
            __builtin_amdgcn_sched_barrier(0);
            pack(ldB, c + 1);                            // waits vmcnt(8)
            __builtin_amdgcn_sched_barrier(0);
            asm volatile("s_waitcnt lgkmcnt(0)" ::: "memory");
            __builtin_amdgcn_s_barrier();                // end round c
            // odd round c+1: issue(c+3)->B, pack(c+2) from A
            if (c + 3 < NSUB) issue(ldB, c + 3);
            __builtin_amdgcn_sched_barrier(0);
            if (c + 2 < NSUB) pack(ldA, c + 2);
            __builtin_amdgcn_sched_barrier(0);
            asm volatile("s_waitcnt lgkmcnt(0)" ::: "memory");
            __builtin_amdgcn_s_barrier();                // end round c+1
        }

        __builtin_amdgcn_s_barrier();                    // wait consumers' red/zl
        // reduce 4 consumer partials, divide by Z, write out
        f32x4 rs = {0.f, 0.f, 0.f, 0.f};
        #pragma unroll
        for (int w2 = 0; w2 < 4; ++w2)
            rs += *(const f32x4*)(red + ((size_t)(w2 * 64 + lane)) * 16 + 4 * w);
        #pragma unroll
        for (int q = 0; q < 4; ++q) {
            const int rit = g * 4 + q;
            const float z = zl[rit] + zl[16 + rit] + zl[32 + rit] + zl[48 + rit];
            out[(size_t)(tile * 16 + rit) * OUT_FEAT + w * 16 + cl] = rs[q] / z;
        }
    } else {
        // ========================= CONSUMER =========================
        const int cw  = w - 4;
        const int row = tile * 16 + cl;
        const float s1r = s1v[row];

        f32x4 acc0 = {0.f, 0.f, 0.f, 0.f};
        f32x4 acc1 = acc0, acc2 = acc0, acc3 = acc0;
        float zacc = 0.f;

        asm volatile("s_waitcnt lgkmcnt(0)" ::: "memory");
        __builtin_amdgcn_s_barrier();                    // B0 (prologue)

        for (int c = 0; c < NSUB; ++c) {
            const char* rbuf = bufs + (c & 1) * BUFSZ;
            #pragma unroll
            for (int kk = 0; kk < KPW; ++kk) {
                const int ks = cw * KPW + kk;            // k-step in sub (0..15)
                const uint2 ab = *(const uint2*)(rbuf + cl * ROWPAD + ks * 32 + 8 * g);
                const float* sp = s2l + c * SUBC + ks * 32 + 8 * g;
                const f32x4 s0  = *(const f32x4*)(sp);
                const f32x4 s1x = *(const f32x4*)(sp + 4);
                const unsigned short* wq = whb + ((size_t)(c * 16 + ks)) * 2048 + lane * 8;
                bf16x8 B0 = *(const bf16x8*)(wq);
                bf16x8 B1 = *(const bf16x8*)(wq + 512);
                bf16x8 B2 = *(const bf16x8*)(wq + 1024);
                bf16x8 B3 = *(const bf16x8*)(wq + 1536);

                bf16x8 af;
                #pragma unroll
                for (int e = 0; e < 4; ++e) {
                    float tv = s1r + s0[e];
                    float el = fmaxf(tv, NEG_SLOPE * tv);
                    float wv = ((ab.x >> (8 * e)) & 1u) ? exp2_fast(el) : 1.0f;
                    zacc += wv;
                    af[e] = f2bf_fast(wv);
                }
                #pragma unroll
                for (int e = 0; e < 4; ++e) {
                    float tv = s1r + s1x[e];
                    float el = fmaxf(tv, NEG_SLOPE * tv);
                    float wv = ((ab.y >> (8 * e)) & 1u) ? exp2_fast(el) : 1.0f;
                    zacc += wv;
                    af[4 + e] = f2bf_fast(wv);
                }

                acc0 = __builtin_amdgcn_mfma_f32_16x16x32_bf16(af, B0, acc0, 0, 0, 0);
                acc1 = __builtin_amdgcn_mfma_f32_16x16x32_bf16(af, B1, acc1, 0, 0, 0);
                acc2 = __builtin_amdgcn_mfma_f32_16x16x32_bf16(af, B2, acc2, 0, 0, 0);
                acc3 = __builtin_amdgcn_mfma_f32_16x16x32_bf16(af, B3, acc3, 0, 0, 0);
            }
            asm volatile("s_waitcnt lgkmcnt(0)" ::: "memory");
            __builtin_amdgcn_s_barrier();                // end round c
        }

        // publish partials (red aliases bufs -- all buf reads are done)
        *(f32x4*)(red + ((size_t)(cw * 64 + lane)) * 16 + 0)  = acc0;
        *(f32x4*)(red + ((size_t)(cw * 64 + lane)) * 16 + 4)  = acc1;
        *(f32x4*)(red + ((size_t)(cw * 64 + lane)) * 16 + 8)  = acc2;
        *(f32x4*)(red + ((size_t)(cw * 64 + lane)) * 16 + 12) = acc3;
        float zz = zacc + __shfl_xor(zacc, 16);
        zz += __shfl_xor(zz, 32);
        if (lane < 16) zl[cw * 16 + lane] = zz;
        asm volatile("s_waitcnt lgkmcnt(0)" ::: "memory");
        __builtin_amdgcn_s_barrier();                    // release producers
    }
}

// ---------------------------------------------------------------------------
extern "C" void kernel_launch(void* const* d_in, const int* in_sizes, int n_in,
                              void* d_out, int out_size, void* d_ws, size_t ws_size,
                              hipStream_t stream) {
    const float* x   = (const float*)d_in[0];
    const int*   adj = (const int*)d_in[1];
    const float* W   = (const float*)d_in[2];
    const float* a   = (const float*)d_in[3];
    float* out = (float*)d_out;

    char* ws = (char*)d_ws;
    float* s1 = (float*)(ws);                                  // 32 KB
    float* s2 = (float*)(ws + 32 * 1024);                      // 32 KB
    unsigned short* whb = (unsigned short*)(ws + 64 * 1024);   // 1 MB

    k_wh   <<<dim3(N_NODES / 4), dim3(256), 0, stream>>>(x, W, a, s1, s2, whb);
    k_fused<<<dim3(TILES), dim3(512), 0, stream>>>(adj, s1, s2, whb, out);
}

// Round 11
// 83.037 us; speedup vs baseline: 1.5750x; 1.0324x over previous
//
#include <hip/hip_runtime.h>
#include <hip/hip_bf16.h>

#define N_NODES 8192
#define IN_FEAT 128
#define OUT_FEAT 64
#define NEG_SLOPE 0.2f
#define TILES (N_NODES / 16)       // 512 row tiles of 16 -> grid, 2 blocks/CU
#define SUBC 512                   // cols per sub-chunk (staged unit)
#define NSUB (N_NODES / SUBC)      // 16 rounds
#define KPW 4                      // k-steps per consumer wave per round
#define ROWPAD 528                 // LDS byte stride per packed row
#define BUFSZ (16 * ROWPAD)        // one adj-byte buffer (8448 B)
#define LOG2E 1.44269504088896340736f

using f32x4  = __attribute__((ext_vector_type(4))) float;
using i32x4  = __attribute__((ext_vector_type(4))) int;
using bf16x8 = __attribute__((ext_vector_type(8))) short;

// float -> bf16 bits RNE (k_wh pack, not hot)
static __device__ __forceinline__ short f2bf(float f) {
    unsigned int u = __float_as_uint(f);
    unsigned int r = (u + 0x7FFFu + ((u >> 16) & 1u)) >> 16;
    return (short)r;
}

// hot-path convert: pairs into v_cvt_pk_bf16_f32
static __device__ __forceinline__ short f2bf_fast(float f) {
    __hip_bfloat16 h = __float2bfloat16(f);
    return __builtin_bit_cast(short, h);
}

static __device__ __forceinline__ float exp2_fast(float x) {
    return __builtin_amdgcn_exp2f(x);
}

// ---------------------------------------------------------------------------
// K1: Wh = x @ W (fp32); s1/s2 = (Wh@a1/a2)*log2e; Wh packed bf16 into MFMA
// B-fragment layout: whb[((jb*4+fg)*64 + gl*16+cl)*8 + e]
//   = bf16(Wh[jb*32 + gl*8 + e][fg*16 + cl])
// ---------------------------------------------------------------------------
__global__ __launch_bounds__(256) void k_wh(
    const float* __restrict__ x, const float* __restrict__ W,
    const float* __restrict__ a,
    float* __restrict__ s1, float* __restrict__ s2,
    unsigned short* __restrict__ whb)
{
    __shared__ float xs[4][IN_FEAT];
    const int wv   = threadIdx.x >> 6;
    const int lane = threadIdx.x & 63;
    const int row  = blockIdx.x * 4 + wv;

    const float2 xv = *(const float2*)(x + (size_t)row * IN_FEAT + lane * 2);
    xs[wv][lane * 2]     = xv.x;
    xs[wv][lane * 2 + 1] = xv.y;
    __syncthreads();

    float acc = 0.f;
    #pragma unroll
    for (int k = 0; k < IN_FEAT; ++k)
        acc = fmaf(xs[wv][k], W[k * OUT_FEAT + lane], acc);

    float p1 = acc * a[lane];
    float p2 = acc * a[OUT_FEAT + lane];
    #pragma unroll
    for (int off = 32; off; off >>= 1) {
        p1 += __shfl_xor(p1, off);
        p2 += __shfl_xor(p2, off);
    }
    if (lane == 0) {
        s1[row] = p1 * LOG2E;
        s2[row] = p2 * LOG2E;
    }

    const int jb = row >> 5;
    const int ri = row & 31;
    const int gl = ri >> 3;
    const int e  = ri & 7;
    const int fg = lane >> 4;
    const int cl = lane & 15;
    whb[(((size_t)(jb * 4 + fg) * 64) + (gl * 16 + cl)) * 8 + e] = (unsigned short)f2bf(acc);
}

// ---------------------------------------------------------------------------
// K2 (fused, producer/consumer, depth-3): waves 0-3 stream adj with PLAIN
// loads (L3-allocating: Infinity Cache is 256MB = |adj|, replays hit L3)
// through a 3-deep reg/LDS ring: at round c, issue(c+3) and pack(c+1) whose
// loads were issued TWO rounds ago (latency budget ~2 rounds, never drains).
// Waves 4-7 compute: vmcnt chain holds only L2-hot whb loads.
// One barrier per round. Block reduces in LDS, writes out directly.
// A-fragment: A[m][k], m=lane&15, k=8*(lane>>4)+e.
// ---------------------------------------------------------------------------
__global__ __launch_bounds__(512, 4) void k_fused(
    const int* __restrict__ adj, const float* __restrict__ s1v,
    const float* __restrict__ s2v, const unsigned short* __restrict__ whb,
    float* __restrict__ out)
{
    __shared__ __align__(16) char lds[3 * BUFSZ + N_NODES * 4 + 256];
    char*  bufs = lds;                                   // 3 x 8448 adj-byte bufs
    float* s2l  = (float*)(lds + 3 * BUFSZ);             // 8192 floats (32 KB)
    float* zl   = (float*)(lds + 3 * BUFSZ + N_NODES * 4);
    float* red  = (float*)lds;                           // aliases bufs (post-loop)

    const int tid  = threadIdx.x;
    const int lane = tid & 63;
    const int w    = tid >> 6;                           // 0..7
    const int tile = blockIdx.x;
    const int cl = lane & 15, g = lane >> 4;

    // ---- s2 -> LDS (all 512 threads, 16 floats each) ----
    {
        const float* src = s2v + tid * 4;
        #pragma unroll
        for (int i = 0; i < 4; ++i)
            *(f32x4*)(s2l + tid * 4 + i * 2048) = *(const f32x4*)(src + i * 2048);
    }

    if (w < 4) {
        // ========================= PRODUCER =========================
        const int* stg = adj + ((size_t)(tile * 16 + w * 4)) * N_NODES + lane * 4;
        i32x4 ldA[8], ldB[8], ldC[8];

        auto issue = [&](i32x4 (&ld)[8], int c) {
            #pragma unroll
            for (int rr = 0; rr < 4; ++rr)
                #pragma unroll
                for (int q = 0; q < 2; ++q)
                    ld[rr * 2 + q] = *(const i32x4*)(
                        stg + (size_t)rr * N_NODES + c * SUBC + q * 256);
        };
        auto pack = [&](i32x4 (&ld)[8], int c) {   // sub-chunk c -> buf[c%3]
            char* wbuf = bufs + (c % 3) * BUFSZ;
            #pragma unroll
            for (int rr = 0; rr < 4; ++rr)
                #pragma unroll
                for (int q = 0; q < 2; ++q) {
                    i32x4 v = ld[rr * 2 + q];
                    unsigned int d = (v[0] > 0 ? 1u : 0u) | (v[1] > 0 ? 0x100u : 0u)
                                   | (v[2] > 0 ? 0x10000u : 0u) | (v[3] > 0 ? 0x1000000u : 0u);
                    *(unsigned int*)(wbuf + (w * 4 + rr) * ROWPAD + q * 256 + lane * 4) = d;
                }
        };
        // round c: issue(iset, c+3); pack(pset, c+1) [issued 2 rounds ago]
        auto round_p = [&](i32x4 (&iset)[8], i32x4 (&pset)[8], int c) {
            if (c + 3 < NSUB) issue(iset, c + 3);
            __builtin_amdgcn_sched_barrier(0);
            if (c + 1 < NSUB) pack(pset, c + 1);
            __builtin_amdgcn_sched_barrier(0);
            asm volatile("s_waitcnt lgkmcnt(0)" ::: "memory");
            __builtin_amdgcn_s_barrier();
        };

        // prologue: 3 sets in flight, pack(0)
        issue(ldA, 0);
        issue(ldB, 1);
        issue(ldC, 2);
        pack(ldA, 0);
        asm volatile("s_waitcnt lgkmcnt(0)" ::: "memory");
        __builtin_amdgcn_s_barrier();                    // B0 (prologue)

        for (int cb = 0; cb < NSUB; cb += 3) {
            round_p(ldA, ldB, cb);
            if (cb + 1 < NSUB) round_p(ldB, ldC, cb + 1);
            if (cb + 2 < NSUB) round_p(ldC, ldA, cb + 2);
        }

        __builtin_amdgcn_s_barrier();                    // wait consumers' red/zl
        // reduce 4 consumer partials, divide by Z, write out
        f32x4 rs = {0.f, 0.f, 0.f, 0.f};
        #pragma unroll
        for (int w2 = 0; w2 < 4; ++w2)
            rs += *(const f32x4*)(red + ((size_t)(w2 * 64 + lane)) * 16 + 4 * w);
        #pragma unroll
        for (int q = 0; q < 4; ++q) {
            const int rit = g * 4 + q;
            const float z = zl[rit] + zl[16 + rit] + zl[32 + rit] + zl[48 + rit];
            out[(size_t)(tile * 16 + rit) * OUT_FEAT + w * 16 + cl] = rs[q] / z;
        }
    } else {
        // ========================= CONSUMER =========================
        const int cw  = w - 4;
        const int row = tile * 16 + cl;
        const float s1r = s1v[row];

        f32x4 acc0 = {0.f, 0.f, 0.f, 0.f};
        f32x4 acc1 = acc0, acc2 = acc0, acc3 = acc0;
        float zacc = 0.f;

        asm volatile("s_waitcnt lgkmcnt(0)" ::: "memory");
        __builtin_amdgcn_s_barrier();                    // B0 (prologue)

        for (int c = 0; c < NSUB; ++c) {
            const char* rbuf = bufs + (c % 3) * BUFSZ;
            #pragma unroll
            for (int kk = 0; kk < KPW; ++kk) {
                const int ks = cw * KPW + kk;            // k-step in sub (0..15)
                const uint2 ab = *(const uint2*)(rbuf + cl * ROWPAD + ks * 32 + 8 * g);
                const float* sp = s2l + c * SUBC + ks * 32 + 8 * g;
                const f32x4 s0  = *(const f32x4*)(sp);
                const f32x4 s1x = *(const f32x4*)(sp + 4);
                const unsigned short* wq = whb + ((size_t)(c * 16 + ks)) * 2048 + lane * 8;
                bf16x8 B0 = *(const bf16x8*)(wq);
                bf16x8 B1 = *(const bf16x8*)(wq + 512);
                bf16x8 B2 = *(const bf16x8*)(wq + 1024);
                bf16x8 B3 = *(const bf16x8*)(wq + 1536);

                bf16x8 af;
                #pragma unroll
                for (int e = 0; e < 4; ++e) {
                    float tv = s1r + s0[e];
                    float el = fmaxf(tv, NEG_SLOPE * tv);
                    float wv = ((ab.x >> (8 * e)) & 1u) ? exp2_fast(el) : 1.0f;
                    zacc += wv;
                    af[e] = f2bf_fast(wv);
                }
                #pragma unroll
                for (int e = 0; e < 4; ++e) {
                    float tv = s1r + s1x[e];
                    float el = fmaxf(tv, NEG_SLOPE * tv);
                    float wv = ((ab.y >> (8 * e)) & 1u) ? exp2_fast(el) : 1.0f;
                    zacc += wv;
                    af[4 + e] = f2bf_fast(wv);
                }

                acc0 = __builtin_amdgcn_mfma_f32_16x16x32_bf16(af, B0, acc0, 0, 0, 0);
                acc1 = __builtin_amdgcn_mfma_f32_16x16x32_bf16(af, B1, acc1, 0, 0, 0);
                acc2 = __builtin_amdgcn_mfma_f32_16x16x32_bf16(af, B2, acc2, 0, 0, 0);
                acc3 = __builtin_amdgcn_mfma_f32_16x16x32_bf16(af, B3, acc3, 0, 0, 0);
            }
            asm volatile("s_waitcnt lgkmcnt(0)" ::: "memory");
            __builtin_amdgcn_s_barrier();                // end round c
        }

        // publish partials (red aliases bufs -- all buf reads are done)
        *(f32x4*)(red + ((size_t)(cw * 64 + lane)) * 16 + 0)  = acc0;
        *(f32x4*)(red + ((size_t)(cw * 64 + lane)) * 16 + 4)  = acc1;
        *(f32x4*)(red + ((size_t)(cw * 64 + lane)) * 16 + 8)  = acc2;
        *(f32x4*)(red + ((size_t)(cw * 64 + lane)) * 16 + 12) = acc3;
        float zz = zacc + __shfl_xor(zacc, 16);
        zz += __shfl_xor(zz, 32);
        if (lane < 16) zl[cw * 16 + lane] = zz;
        asm volatile("s_waitcnt lgkmcnt(0)" ::: "memory");
        __builtin_amdgcn_s_barrier();                    // release producers
    }
}

// ---------------------------------------------------------------------------
extern "C" void kernel_launch(void* const* d_in, const int* in_sizes, int n_in,
                              void* d_out, int out_size, void* d_ws, size_t ws_size,
                              hipStream_t stream) {
    const float* x   = (const float*)d_in[0];
    const int*   adj = (const int*)d_in[1];
    const float* W   = (const float*)d_in[2];
    const float* a   = (const float*)d_in[3];
    float* out = (float*)d_out;

    char* ws = (char*)d_ws;
    float* s1 = (float*)(ws);                                  // 32 KB
    float* s2 = (float*)(ws + 32 * 1024);                      // 32 KB
    unsigned short* whb = (unsigned short*)(ws + 64 * 1024);   // 1 MB

    k_wh   <<<dim3(N_NODES / 4), dim3(256), 0, stream>>>(x, W, a, s1, s2, whb);
    k_fused<<<dim3(TILES), dim3(512), 0, stream>>>(adj, s1, s2, whb, out);
}

// Round 12
// 74.344 us; speedup vs baseline: 1.7591x; 1.1169x over previous
//
#include <hip/hip_runtime.h>
#include <hip/hip_bf16.h>

#define N_NODES 8192
#define IN_FEAT 128
#define OUT_FEAT 64
#define NEG_SLOPE 0.2f
#define TILES (N_NODES / 16)       // 512 row tiles of 16 -> grid, 3 blocks/CU
#define SUBC 256                   // cols per sub-chunk (staged unit)
#define NSUB (N_NODES / SUBC)      // 32 rounds
#define KPW 2                      // k-steps per consumer wave per round (8/4)
#define ROWPAD 272                 // LDS byte stride per packed row (256+16)
#define BUFSZ (16 * ROWPAD)        // one adj-byte buffer (4352 B)
#define LOG2E 1.44269504088896340736f

using f32x4  = __attribute__((ext_vector_type(4))) float;
using i32x4  = __attribute__((ext_vector_type(4))) int;
using bf16x8 = __attribute__((ext_vector_type(8))) short;

// float -> bf16 bits RNE (k_wh pack, not hot)
static __device__ __forceinline__ short f2bf(float f) {
    unsigned int u = __float_as_uint(f);
    unsigned int r = (u + 0x7FFFu + ((u >> 16) & 1u)) >> 16;
    return (short)r;
}

// hot-path convert: pairs into v_cvt_pk_bf16_f32
static __device__ __forceinline__ short f2bf_fast(float f) {
    __hip_bfloat16 h = __float2bfloat16(f);
    return __builtin_bit_cast(short, h);
}

static __device__ __forceinline__ float exp2_fast(float x) {
    return __builtin_amdgcn_exp2f(x);
}

// ---------------------------------------------------------------------------
// K1: Wh = x @ W (fp32); s1/s2 = (Wh@a1/a2)*log2e; Wh packed bf16 into MFMA
// B-fragment layout: whb[((jb*4+fg)*64 + gl*16+cl)*8 + e]
//   = bf16(Wh[jb*32 + gl*8 + e][fg*16 + cl])
// ---------------------------------------------------------------------------
__global__ __launch_bounds__(256) void k_wh(
    const float* __restrict__ x, const float* __restrict__ W,
    const float* __restrict__ a,
    float* __restrict__ s1, float* __restrict__ s2,
    unsigned short* __restrict__ whb)
{
    __shared__ float xs[4][IN_FEAT];
    const int wv   = threadIdx.x >> 6;
    const int lane = threadIdx.x & 63;
    const int row  = blockIdx.x * 4 + wv;

    const float2 xv = *(const float2*)(x + (size_t)row * IN_FEAT + lane * 2);
    xs[wv][lane * 2]     = xv.x;
    xs[wv][lane * 2 + 1] = xv.y;
    __syncthreads();

    float acc = 0.f;
    #pragma unroll
    for (int k = 0; k < IN_FEAT; ++k)
        acc = fmaf(xs[wv][k], W[k * OUT_FEAT + lane], acc);

    float p1 = acc * a[lane];
    float p2 = acc * a[OUT_FEAT + lane];
    #pragma unroll
    for (int off = 32; off; off >>= 1) {
        p1 += __shfl_xor(p1, off);
        p2 += __shfl_xor(p2, off);
    }
    if (lane == 0) {
        s1[row] = p1 * LOG2E;
        s2[row] = p2 * LOG2E;
    }

    const int jb = row >> 5;
    const int ri = row & 31;
    const int gl = ri >> 3;
    const int e  = ri & 7;
    const int fg = lane >> 4;
    const int cl = lane & 15;
    whb[(((size_t)(jb * 4 + fg) * 64) + (gl * 16 + cl)) * 8 + e] = (unsigned short)f2bf(acc);
}

// ---------------------------------------------------------------------------
// K2 (fused, producer/consumer, 3 blocks/CU): waves 0-3 stream adj (one row
// each of 4 rows, 1KB/instr plain loads) through a 2-deep reg ring; waves 4-7
// compute (whb-only vmcnt chains). 32 rounds of SUBC=256 cols. Low VGPR
// (ring = 2 sets x 4 x i32x4 = 32) so __launch_bounds__(512,6) fits ->
// 24 waves/CU = 12 streaming waves (k_cmp evidence: stream count is the
// read-BW lever). Block reduces in LDS (red aliases s2l), writes out.
// A-fragment: A[m][k], m=lane&15, k=8*(lane>>4)+e.
// ---------------------------------------------------------------------------
__global__ __launch_bounds__(512, 6) void k_fused(
    const int* __restrict__ adj, const float* __restrict__ s1v,
    const float* __restrict__ s2v, const unsigned short* __restrict__ whb,
    float* __restrict__ out)
{
    __shared__ __align__(16) char lds[2 * BUFSZ + N_NODES * 4 + 256];
    char*  bufs = lds;                                   // 2 x 4352 adj-byte bufs
    float* s2l  = (float*)(lds + 2 * BUFSZ);             // 8192 floats (32 KB)
    float* zl   = (float*)(lds + 2 * BUFSZ + N_NODES * 4);
    float* red  = s2l;                                   // aliases s2l (post-loop)

    const int tid  = threadIdx.x;
    const int lane = tid & 63;
    const int w    = tid >> 6;                           // 0..7
    const int tile = blockIdx.x;
    const int cl = lane & 15, g = lane >> 4;

    // ---- s2 -> LDS (all 512 threads, 16 floats each) ----
    {
        const float* src = s2v + tid * 4;
        #pragma unroll
        for (int i = 0; i < 4; ++i)
            *(f32x4*)(s2l + tid * 4 + i * 2048) = *(const f32x4*)(src + i * 2048);
    }

    if (w < 4) {
        // ========================= PRODUCER =========================
        // wave w streams rows 4w..4w+3, ONE 1KB load per row per round
        const int* stg = adj + ((size_t)(tile * 16 + w * 4)) * N_NODES + lane * 4;
        i32x4 ldA[4], ldB[4];

        auto issue = [&](i32x4 (&ld)[4], int c) {
            #pragma unroll
            for (int rr = 0; rr < 4; ++rr)
                ld[rr] = *(const i32x4*)(stg + (size_t)rr * N_NODES + c * SUBC);
        };
        auto pack = [&](i32x4 (&ld)[4], int c) {   // sub-chunk c -> buf[c&1]
            char* wbuf = bufs + (c & 1) * BUFSZ;
            #pragma unroll
            for (int rr = 0; rr < 4; ++rr) {
                i32x4 v = ld[rr];
                unsigned int d = (v[0] > 0 ? 1u : 0u) | (v[1] > 0 ? 0x100u : 0u)
                               | (v[2] > 0 ? 0x10000u : 0u) | (v[3] > 0 ? 0x1000000u : 0u);
                *(unsigned int*)(wbuf + (w * 4 + rr) * ROWPAD + lane * 4) = d;
            }
        };

        // prologue: A<-0, B<-1 in flight; pack(0)
        issue(ldA, 0);
        issue(ldB, 1);
        pack(ldA, 0);
        asm volatile("s_waitcnt lgkmcnt(0)" ::: "memory");
        __builtin_amdgcn_s_barrier();                    // B0 (prologue)

        for (int c = 0; c < NSUB; c += 2) {
            // even round c: issue(c+2)->A, pack(c+1) from B
            if (c + 2 < NSUB) issue(ldA, c + 2);
            __builtin_amdgcn_sched_barrier(0);
            pack(ldB, c + 1);
            __builtin_amdgcn_sched_barrier(0);
            asm volatile("s_waitcnt lgkmcnt(0)" ::: "memory");
            __builtin_amdgcn_s_barrier();                // end round c
            // odd round c+1: issue(c+3)->B, pack(c+2) from A
            if (c + 3 < NSUB) issue(ldB, c + 3);
            __builtin_amdgcn_sched_barrier(0);
            if (c + 2 < NSUB) pack(ldA, c + 2);
            __builtin_amdgcn_sched_barrier(0);
            asm volatile("s_waitcnt lgkmcnt(0)" ::: "memory");
            __builtin_amdgcn_s_barrier();                // end round c+1
        }

        __builtin_amdgcn_s_barrier();                    // wait consumers' red/zl
        // reduce 4 consumer partials, divide by Z, write out
        f32x4 rs = {0.f, 0.f, 0.f, 0.f};
        #pragma unroll
        for (int w2 = 0; w2 < 4; ++w2)
            rs += *(const f32x4*)(red + ((size_t)(w2 * 64 + lane)) * 16 + 4 * w);
        #pragma unroll
        for (int q = 0; q < 4; ++q) {
            const int rit = g * 4 + q;
            const float z = zl[rit] + zl[16 + rit] + zl[32 + rit] + zl[48 + rit];
            out[(size_t)(tile * 16 + rit) * OUT_FEAT + w * 16 + cl] = rs[q] / z;
        }
    } else {
        // ========================= CONSUMER =========================
        const int cw  = w - 4;
        const int row = tile * 16 + cl;
        const float s1r = s1v[row];

        f32x4 acc0 = {0.f, 0.f, 0.f, 0.f};
        f32x4 acc1 = acc0, acc2 = acc0, acc3 = acc0;
        float zacc = 0.f;

        asm volatile("s_waitcnt lgkmcnt(0)" ::: "memory");
        __builtin_amdgcn_s_barrier();                    // B0 (prologue)

        for (int c = 0; c < NSUB; ++c) {
            const char* rbuf = bufs + (c & 1) * BUFSZ;
            #pragma unroll
            for (int kk = 0; kk < KPW; ++kk) {
                const int ks = cw * KPW + kk;            // k-step in sub (0..7)
                const uint2 ab = *(const uint2*)(rbuf + cl * ROWPAD + ks * 32 + 8 * g);
                const float* sp = s2l + c * SUBC + ks * 32 + 8 * g;
                const f32x4 s0  = *(const f32x4*)(sp);
                const f32x4 s1x = *(const f32x4*)(sp + 4);
                const unsigned short* wq = whb + ((size_t)(c * 8 + ks)) * 2048 + lane * 8;
                bf16x8 B0 = *(const bf16x8*)(wq);
                bf16x8 B1 = *(const bf16x8*)(wq + 512);
                bf16x8 B2 = *(const bf16x8*)(wq + 1024);
                bf16x8 B3 = *(const bf16x8*)(wq + 1536);

                bf16x8 af;
                #pragma unroll
                for (int e = 0; e < 4; ++e) {
                    float tv = s1r + s0[e];
                    float el = fmaxf(tv, NEG_SLOPE * tv);
                    float wv = ((ab.x >> (8 * e)) & 1u) ? exp2_fast(el) : 1.0f;
                    zacc += wv;
                    af[e] = f2bf_fast(wv);
                }
                #pragma unroll
                for (int e = 0; e < 4; ++e) {
                    float tv = s1r + s1x[e];
                    float el = fmaxf(tv, NEG_SLOPE * tv);
                    float wv = ((ab.y >> (8 * e)) & 1u) ? exp2_fast(el) : 1.0f;
                    zacc += wv;
                    af[4 + e] = f2bf_fast(wv);
                }

                acc0 = __builtin_amdgcn_mfma_f32_16x16x32_bf16(af, B0, acc0, 0, 0, 0);
                acc1 = __builtin_amdgcn_mfma_f32_16x16x32_bf16(af, B1, acc1, 0, 0, 0);
                acc2 = __builtin_amdgcn_mfma_f32_16x16x32_bf16(af, B2, acc2, 0, 0, 0);
                acc3 = __builtin_amdgcn_mfma_f32_16x16x32_bf16(af, B3, acc3, 0, 0, 0);
            }
            asm volatile("s_waitcnt lgkmcnt(0)" ::: "memory");
            __builtin_amdgcn_s_barrier();                // end round c
        }

        // publish partials into red (aliases s2l; all s2l reads are done)
        *(f32x4*)(red + ((size_t)(cw * 64 + lane)) * 16 + 0)  = acc0;
        *(f32x4*)(red + ((size_t)(cw * 64 + lane)) * 16 + 4)  = acc1;
        *(f32x4*)(red + ((size_t)(cw * 64 + lane)) * 16 + 8)  = acc2;
        *(f32x4*)(red + ((size_t)(cw * 64 + lane)) * 16 + 12) = acc3;
        float zz = zacc + __shfl_xor(zacc, 16);
        zz += __shfl_xor(zz, 32);
        if (lane < 16) zl[cw * 16 + lane] = zz;
        asm volatile("s_waitcnt lgkmcnt(0)" ::: "memory");
        __builtin_amdgcn_s_barrier();                    // release producers
    }
}

// ---------------------------------------------------------------------------
extern "C" void kernel_launch(void* const* d_in, const int* in_sizes, int n_in,
                              void* d_out, int out_size, void* d_ws, size_t ws_size,
                              hipStream_t stream) {
    const float* x   = (const float*)d_in[0];
    const int*   adj = (const int*)d_in[1];
    const float* W   = (const float*)d_in[2];
    const float* a   = (const float*)d_in[3];
    float* out = (float*)d_out;

    char* ws = (char*)d_ws;
    float* s1 = (float*)(ws);                                  // 32 KB
    float* s2 = (float*)(ws + 32 * 1024);                      // 32 KB
    unsigned short* whb = (unsigned short*)(ws + 64 * 1024);   // 1 MB

    k_wh   <<<dim3(N_NODES / 4), dim3(256), 0, stream>>>(x, W, a, s1, s2, whb);
    k_fused<<<dim3(TILES), dim3(512), 0, stream>>>(adj, s1, s2, whb, out);
}